// Round 1
// baseline (114.733 us; speedup 1.0000x reference)
//
#include <hip/hip_runtime.h>
#include <hip/hip_bf16.h>
#include <cstdint>
#include <cstddef>

#define N_NODES 8192
#define F_IN 512
#define F_OUT 64
#define GAT_ALPHA 0.2f

typedef __attribute__((ext_vector_type(8))) short short8v;  // 8 bf16 = 4 VGPRs
typedef __attribute__((ext_vector_type(4))) float f32x4;

static __device__ __forceinline__ unsigned short f2bf(float f) {
    union { float f; unsigned u; } v; v.f = f;
    unsigned u = v.u + 0x7FFFu + ((v.u >> 16) & 1u);   // RNE
    return (unsigned short)(u >> 16);
}
static __device__ __forceinline__ float bf2f(unsigned short b) {
    union { unsigned u; float f; } v; v.u = ((unsigned)b) << 16;
    return v.f;
}

// Kernel 1: Wh = x @ W (f32), s1 = Wh@a1, s2 = Wh@a2, and fragment-ordered
// bf16 Wh^T:  whtf[jtile][ftile][lane][i] = bf16(Wh[jt*32 + 8*(lane>>4) + i][ft*16 + (lane&15)])
// so kernel 2's B-fragment load is one coalesced 16B load per lane.
__global__ __launch_bounds__(256)
void gat_prep(const float* __restrict__ x, const float* __restrict__ weight,
              const float* __restrict__ a,
              unsigned short* __restrict__ whtf,
              float* __restrict__ s1, float* __restrict__ s2) {
    __shared__ float xs[16 * F_IN];           // 32 KB: 16 rows of x
    __shared__ unsigned short tr[F_OUT][16];  // 2 KB: bf16 Wh tile, [f][row]
    const int tid = threadIdx.x;
    const int lane = tid & 63;
    const int wv = tid >> 6;                  // wave 0..3
    const int r0 = blockIdx.x * 16;

    // stage 16 rows of x (coalesced float4)
    const float4* xg = (const float4*)(x + (size_t)r0 * F_IN);
    float4* xl = (float4*)xs;
    #pragma unroll
    for (int q = 0; q < 8; ++q) xl[tid + q * 256] = xg[tid + q * 256];
    __syncthreads();

    const float a1 = a[lane], a2 = a[64 + lane];
    #pragma unroll
    for (int p = 0; p < 4; ++p) {
        const int rl = p * 4 + wv;            // local row 0..15
        const float* xr = xs + rl * F_IN;
        float acc = 0.f;
        for (int k = 0; k < F_IN; k += 4) {
            float4 xv = *(const float4*)(xr + k);
            acc = fmaf(xv.x, weight[(k + 0) * F_OUT + lane], acc);
            acc = fmaf(xv.y, weight[(k + 1) * F_OUT + lane], acc);
            acc = fmaf(xv.z, weight[(k + 2) * F_OUT + lane], acc);
            acc = fmaf(xv.w, weight[(k + 3) * F_OUT + lane], acc);
        }
        // s1/s2: reduce acc*a over the 64 f-lanes of this row
        float v1 = acc * a1, v2 = acc * a2;
        for (int off = 32; off > 0; off >>= 1) {
            v1 += __shfl_down(v1, off);
            v2 += __shfl_down(v2, off);
        }
        if (lane == 0) { s1[r0 + rl] = v1; s2[r0 + rl] = v2; }
        tr[lane][rl] = f2bf(acc);
    }
    __syncthreads();

    // write the fragment-ordered bf16 tile (2 KB per block, coalesced 16B chunks)
    if (tid < 128) {
        const int ft = tid >> 5;              // 0..3
        const int c  = (tid >> 1) & 15;       // 0..15 (col within ftile)
        const int gg = tid & 1;               // 0..1
        const int jt = r0 >> 5;               // j-tile index
        const int G  = (r0 & 31) >> 3;        // 0 or 2: which lane-group pair
        const short8v sv = *(const short8v*)(&tr[ft * 16 + c][gg * 8]);
        size_t dst = ((size_t)jt * 4 + ft) * 512 + (size_t)(16 * (G + gg) + c) * 8;
        *(short8v*)(whtf + dst) = sv;
    }
}

// Kernel 2: fused masked-softmax attention + PV via bf16 MFMA.
// Block = 512 threads (8 waves). Block owns 16 output rows; wave w owns
// j in [w*1024, (w+1)*1024). No barriers in the main loop.
__global__ __launch_bounds__(512)
void gat_main(const int* __restrict__ adj, const unsigned short* __restrict__ whtf,
              const float* __restrict__ s1, const float* __restrict__ s2,
              float* __restrict__ out) {
    __shared__ float nums[8][16][64];   // 32 KB partial numerators
    __shared__ float dens[8][16];       // partial denominators
    const int tid  = threadIdx.x;
    const int lane = tid & 63;
    const int wv   = tid >> 6;          // 0..7: j-split
    const int l15  = lane & 15, g = lane >> 4;
    const int r0   = blockIdx.x * 16;
    const int row  = r0 + l15;
    const float s1r = s1[row];
    const int j0 = wv * 1024;

    const int*   ap  = adj + (size_t)row * N_NODES + j0 + g * 8;
    const float* s2p = s2 + j0 + g * 8;
    const unsigned short* bp = whtf + ((size_t)(j0 >> 5) * 4) * 512 + (size_t)lane * 8;

    f32x4 acc0 = {0.f, 0.f, 0.f, 0.f};
    f32x4 acc1 = acc0, acc2 = acc0, acc3 = acc0;
    float dsum = 0.f;

    for (int t = 0; t < 32; ++t) {
        int4   aj0 = *(const int4*)ap;
        int4   aj1 = *(const int4*)(ap + 4);
        float4 sa  = *(const float4*)s2p;
        float4 sb  = *(const float4*)(s2p + 4);
        short8v afrag;
        float e, w;
        unsigned short hb;
        #define GAT_EL(idx, ajv, s2v) do { \
            e = s1r + (s2v); e = e > 0.f ? e : GAT_ALPHA * e; \
            w = (ajv) > 0 ? __expf(e) : 0.f; \
            hb = f2bf(w); dsum += bf2f(hb); afrag[idx] = (short)hb; } while (0);
        GAT_EL(0, aj0.x, sa.x) GAT_EL(1, aj0.y, sa.y)
        GAT_EL(2, aj0.z, sa.z) GAT_EL(3, aj0.w, sa.w)
        GAT_EL(4, aj1.x, sb.x) GAT_EL(5, aj1.y, sb.y)
        GAT_EL(6, aj1.z, sb.z) GAT_EL(7, aj1.w, sb.w)
        #undef GAT_EL

        short8v b0 = *(const short8v*)(bp);
        short8v b1 = *(const short8v*)(bp + 512);
        short8v b2 = *(const short8v*)(bp + 1024);
        short8v b3 = *(const short8v*)(bp + 1536);
        acc0 = __builtin_amdgcn_mfma_f32_16x16x32_bf16(afrag, b0, acc0, 0, 0, 0);
        acc1 = __builtin_amdgcn_mfma_f32_16x16x32_bf16(afrag, b1, acc1, 0, 0, 0);
        acc2 = __builtin_amdgcn_mfma_f32_16x16x32_bf16(afrag, b2, acc2, 0, 0, 0);
        acc3 = __builtin_amdgcn_mfma_f32_16x16x32_bf16(afrag, b3, acc3, 0, 0, 0);

        ap += 32; s2p += 32; bp += 2048;
    }

    // row-sum of dsum across the 4 k-groups (lanes with same l15)
    dsum += __shfl_xor(dsum, 16);
    dsum += __shfl_xor(dsum, 32);

    // C-frag layout (verified m89): col = lane&15, row = 4*(lane>>4) + reg
    #pragma unroll
    for (int r = 0; r < 4; ++r) {
        nums[wv][g * 4 + r][0 * 16 + l15] = acc0[r];
        nums[wv][g * 4 + r][1 * 16 + l15] = acc1[r];
        nums[wv][g * 4 + r][2 * 16 + l15] = acc2[r];
        nums[wv][g * 4 + r][3 * 16 + l15] = acc3[r];
    }
    if (lane < 16) dens[wv][lane] = dsum;
    __syncthreads();

    // combine the 8 j-partials, normalize, ELU, write
    for (int o = tid; o < 16 * 64; o += 512) {
        const int r = o >> 6, f = o & 63;
        float num = 0.f, den = 0.f;
        #pragma unroll
        for (int q = 0; q < 8; ++q) { num += nums[q][r][f]; den += dens[q][r]; }
        float h = num / den;
        out[(size_t)(r0 + r) * 64 + f] = h > 0.f ? h : __expf(h) - 1.f;
    }
}

extern "C" void kernel_launch(void* const* d_in, const int* in_sizes, int n_in,
                              void* d_out, int out_size, void* d_ws, size_t ws_size,
                              hipStream_t stream) {
    const float* x      = (const float*)d_in[0];
    const int*   adj    = (const int*)d_in[1];
    const float* weight = (const float*)d_in[2];
    const float* a      = (const float*)d_in[3];
    float* out = (float*)d_out;

    // ws layout: whtf (1 MB bf16) | s1 (32 KB) | s2 (32 KB)
    unsigned short* whtf = (unsigned short*)d_ws;
    float* s1 = (float*)((char*)d_ws + (size_t)N_NODES * F_OUT * 2);
    float* s2 = s1 + N_NODES;

    gat_prep<<<N_NODES / 16, 256, 0, stream>>>(x, weight, a, whtf, s1, s2);
    gat_main<<<N_NODES / 16, 512, 0, stream>>>(adj, whtf, s1, s2, out);
}

// Round 2
// 105.150 us; speedup vs baseline: 1.0911x; 1.0911x over previous
//
#include <hip/hip_runtime.h>
#include <hip/hip_bf16.h>
#include <cstdint>
#include <cstddef>

#define N_NODES 8192
#define F_IN 512
#define F_OUT 64
#define GAT_ALPHA 0.2f

typedef __attribute__((ext_vector_type(8))) short short8v;  // 8 bf16 = 4 VGPRs
typedef __attribute__((ext_vector_type(4))) float f32x4;

static __device__ __forceinline__ unsigned short f2bf(float f) {
    union { float f; unsigned u; } v; v.f = f;
    unsigned u = v.u + 0x7FFFu + ((v.u >> 16) & 1u);   // RNE
    return (unsigned short)(u >> 16);
}
static __device__ __forceinline__ float bf2f(unsigned short b) {
    union { unsigned u; float f; } v; v.u = ((unsigned)b) << 16;
    return v.f;
}

// ---------------------------------------------------------------------------
// Kernel 0: convert W (512x64 f32) into fragment-ordered bf16 hi/lo buffers.
// Tile (kt,ct): lane l holds W[kt*32 + (l>>4)*8 + i][ct*16 + (l&15)], i=0..7.
// whf/wlf[(kt*4+ct)*512 + l*8 + i]. 64 tiles total.
// ---------------------------------------------------------------------------
__global__ __launch_bounds__(256)
void gat_wconv(const float* __restrict__ W, unsigned short* __restrict__ whf,
               unsigned short* __restrict__ wlf) {
    const int t = blockIdx.x * 256 + threadIdx.x;   // 0..4095
    const int tile = t >> 6, lane = t & 63;
    const int kt = tile >> 2, ct = tile & 3;
    const int k0 = kt * 32 + ((lane >> 4) << 3);
    const int c  = ct * 16 + (lane & 15);
    short8v h, l;
    #pragma unroll
    for (int i = 0; i < 8; ++i) {
        float v = W[(size_t)(k0 + i) * F_OUT + c];
        unsigned short hb = f2bf(v);
        h[i] = (short)hb;
        l[i] = (short)f2bf(v - bf2f(hb));
    }
    const size_t dst = (size_t)tile * 512 + (size_t)lane * 8;
    *(short8v*)(whf + dst) = h;
    *(short8v*)(wlf + dst) = l;
}

// ---------------------------------------------------------------------------
// Kernel 1: Wh = x@W via bf16 hi/lo split MFMA (f32-accurate to ~1e-4),
// s1 = Wh@a1, s2 = Wh@a2, and fragment-ordered bf16 whtf for gat_main.
// 256 blocks (1 jtile = 32 rows each) x 128 threads (2 waves, 16 rows/wave).
// ---------------------------------------------------------------------------
__global__ __launch_bounds__(128)
void gat_prep(const float* __restrict__ x, const unsigned short* __restrict__ whf,
              const unsigned short* __restrict__ wlf, const float* __restrict__ a,
              unsigned short* __restrict__ whtf,
              float* __restrict__ s1, float* __restrict__ s2) {
    __shared__ unsigned short ldsT[64][40];   // [col][row], 80B rows: 16B-aligned, 2-way banks only
    const int tid = threadIdx.x;
    const int lane = tid & 63;
    const int wv = tid >> 6;                  // 0..1
    const int l15 = lane & 15, g = lane >> 4;
    const int jt = blockIdx.x;                // jtile 0..255
    const int row0 = jt * 32 + wv * 16;

    f32x4 acc[4] = {{0.f,0.f,0.f,0.f},{0.f,0.f,0.f,0.f},{0.f,0.f,0.f,0.f},{0.f,0.f,0.f,0.f}};

    const float* xp = x + (size_t)(row0 + l15) * F_IN + g * 8;
    for (int kt = 0; kt < 16; ++kt) {
        float4 v0 = *(const float4*)(xp);
        float4 v1 = *(const float4*)(xp + 4);
        xp += 32;
        float vv[8] = {v0.x, v0.y, v0.z, v0.w, v1.x, v1.y, v1.z, v1.w};
        short8v xh, xl;
        #pragma unroll
        for (int i = 0; i < 8; ++i) {
            unsigned short hb = f2bf(vv[i]);
            xh[i] = (short)hb;
            xl[i] = (short)f2bf(vv[i] - bf2f(hb));
        }
        const unsigned short* wp = whf + (size_t)(kt * 4) * 512 + (size_t)lane * 8;
        const unsigned short* lp = wlf + (size_t)(kt * 4) * 512 + (size_t)lane * 8;
        #pragma unroll
        for (int ct = 0; ct < 4; ++ct) {
            short8v wh = *(const short8v*)(wp + ct * 512);
            short8v wl = *(const short8v*)(lp + ct * 512);
            acc[ct] = __builtin_amdgcn_mfma_f32_16x16x32_bf16(xh, wh, acc[ct], 0, 0, 0);
            acc[ct] = __builtin_amdgcn_mfma_f32_16x16x32_bf16(xl, wh, acc[ct], 0, 0, 0);
            acc[ct] = __builtin_amdgcn_mfma_f32_16x16x32_bf16(xh, wl, acc[ct], 0, 0, 0);
        }
    }

    // s1/s2: C-frag is col = ct*16+l15, local row = 4g+r
    #pragma unroll
    for (int r = 0; r < 4; ++r) {
        float p1 = 0.f, p2 = 0.f;
        #pragma unroll
        for (int ct = 0; ct < 4; ++ct) {
            p1 = fmaf(acc[ct][r], a[ct * 16 + l15], p1);
            p2 = fmaf(acc[ct][r], a[64 + ct * 16 + l15], p2);
        }
        p1 += __shfl_xor(p1, 1); p2 += __shfl_xor(p2, 1);
        p1 += __shfl_xor(p1, 2); p2 += __shfl_xor(p2, 2);
        p1 += __shfl_xor(p1, 4); p2 += __shfl_xor(p2, 4);
        p1 += __shfl_xor(p1, 8); p2 += __shfl_xor(p2, 8);
        if (l15 == 0) {
            s1[row0 + g * 4 + r] = p1;
            s2[row0 + g * 4 + r] = p2;
        }
    }

    // transpose to [col][row] bf16 in LDS (8B packed writes, 2-way banks = free)
    #pragma unroll
    for (int ct = 0; ct < 4; ++ct) {
        ushort4 pk;
        pk.x = f2bf(acc[ct][0]); pk.y = f2bf(acc[ct][1]);
        pk.z = f2bf(acc[ct][2]); pk.w = f2bf(acc[ct][3]);
        *(ushort4*)&ldsT[ct * 16 + l15][wv * 16 + g * 4] = pk;
    }
    __syncthreads();

    // emit fragment-ordered whtf: lane l holds Wh[jt*32 + 8*(l>>4)+i][ft*16 + (l&15)]
    #pragma unroll
    for (int fl = 0; fl < 2; ++fl) {
        const int ft = wv * 2 + fl;
        short8v sv = *(const short8v*)&ldsT[ft * 16 + l15][g * 8];
        *(short8v*)(whtf + ((size_t)jt * 4 + ft) * 512 + (size_t)lane * 8) = sv;
    }
}

// ---------------------------------------------------------------------------
// Kernel 2: fused masked-softmax attention + PV via bf16 MFMA. (unchanged)
// Block = 512 threads (8 waves). Block owns 16 output rows; wave w owns
// j in [w*1024, (w+1)*1024). No barriers in the main loop.
// ---------------------------------------------------------------------------
__global__ __launch_bounds__(512)
void gat_main(const int* __restrict__ adj, const unsigned short* __restrict__ whtf,
              const float* __restrict__ s1, const float* __restrict__ s2,
              float* __restrict__ out) {
    __shared__ float nums[8][16][64];   // 32 KB partial numerators
    __shared__ float dens[8][16];       // partial denominators
    const int tid  = threadIdx.x;
    const int lane = tid & 63;
    const int wv   = tid >> 6;          // 0..7: j-split
    const int l15  = lane & 15, g = lane >> 4;
    const int r0   = blockIdx.x * 16;
    const int row  = r0 + l15;
    const float s1r = s1[row];
    const int j0 = wv * 1024;

    const int*   ap  = adj + (size_t)row * N_NODES + j0 + g * 8;
    const float* s2p = s2 + j0 + g * 8;
    const unsigned short* bp = whtf + ((size_t)(j0 >> 5) * 4) * 512 + (size_t)lane * 8;

    f32x4 acc0 = {0.f, 0.f, 0.f, 0.f};
    f32x4 acc1 = acc0, acc2 = acc0, acc3 = acc0;
    float dsum = 0.f;

    for (int t = 0; t < 32; ++t) {
        int4   aj0 = *(const int4*)ap;
        int4   aj1 = *(const int4*)(ap + 4);
        float4 sa  = *(const float4*)s2p;
        float4 sb  = *(const float4*)(s2p + 4);
        short8v afrag;
        float e, w;
        unsigned short hb;
        #define GAT_EL(idx, ajv, s2v) do { \
            e = s1r + (s2v); e = e > 0.f ? e : GAT_ALPHA * e; \
            w = (ajv) > 0 ? __expf(e) : 0.f; \
            hb = f2bf(w); dsum += bf2f(hb); afrag[idx] = (short)hb; } while (0);
        GAT_EL(0, aj0.x, sa.x) GAT_EL(1, aj0.y, sa.y)
        GAT_EL(2, aj0.z, sa.z) GAT_EL(3, aj0.w, sa.w)
        GAT_EL(4, aj1.x, sb.x) GAT_EL(5, aj1.y, sb.y)
        GAT_EL(6, aj1.z, sb.z) GAT_EL(7, aj1.w, sb.w)
        #undef GAT_EL

        short8v b0 = *(const short8v*)(bp);
        short8v b1 = *(const short8v*)(bp + 512);
        short8v b2 = *(const short8v*)(bp + 1024);
        short8v b3 = *(const short8v*)(bp + 1536);
        acc0 = __builtin_amdgcn_mfma_f32_16x16x32_bf16(afrag, b0, acc0, 0, 0, 0);
        acc1 = __builtin_amdgcn_mfma_f32_16x16x32_bf16(afrag, b1, acc1, 0, 0, 0);
        acc2 = __builtin_amdgcn_mfma_f32_16x16x32_bf16(afrag, b2, acc2, 0, 0, 0);
        acc3 = __builtin_amdgcn_mfma_f32_16x16x32_bf16(afrag, b3, acc3, 0, 0, 0);

        ap += 32; s2p += 32; bp += 2048;
    }

    // row-sum of dsum across the 4 k-groups (lanes with same l15)
    dsum += __shfl_xor(dsum, 16);
    dsum += __shfl_xor(dsum, 32);

    // C-frag layout (verified m89): col = lane&15, row = 4*(lane>>4) + reg
    #pragma unroll
    for (int r = 0; r < 4; ++r) {
        nums[wv][g * 4 + r][0 * 16 + l15] = acc0[r];
        nums[wv][g * 4 + r][1 * 16 + l15] = acc1[r];
        nums[wv][g * 4 + r][2 * 16 + l15] = acc2[r];
        nums[wv][g * 4 + r][3 * 16 + l15] = acc3[r];
    }
    if (lane < 16) dens[wv][lane] = dsum;
    __syncthreads();

    // combine the 8 j-partials, normalize, ELU, write
    for (int o = tid; o < 16 * 64; o += 512) {
        const int r = o >> 6, f = o & 63;
        float num = 0.f, den = 0.f;
        #pragma unroll
        for (int q = 0; q < 8; ++q) { num += nums[q][r][f]; den += dens[q][r]; }
        float h = num / den;
        out[(size_t)(r0 + r) * 64 + f] = h > 0.f ? h : __expf(h) - 1.f;
    }
}

extern "C" void kernel_launch(void* const* d_in, const int* in_sizes, int n_in,
                              void* d_out, int out_size, void* d_ws, size_t ws_size,
                              hipStream_t stream) {
    const float* x      = (const float*)d_in[0];
    const int*   adj    = (const int*)d_in[1];
    const float* weight = (const float*)d_in[2];
    const float* a      = (const float*)d_in[3];
    float* out = (float*)d_out;

    // ws layout: whtf (1 MB) | s1 (32 KB) | s2 (32 KB) | whf (64 KB) | wlf (64 KB)
    char* ws = (char*)d_ws;
    unsigned short* whtf = (unsigned short*)ws;
    float* s1            = (float*)(ws + 1048576);
    float* s2            = (float*)(ws + 1048576 + 32768);
    unsigned short* whf  = (unsigned short*)(ws + 1048576 + 65536);
    unsigned short* wlf  = (unsigned short*)(ws + 1048576 + 65536 + 65536);

    gat_wconv<<<16, 256, 0, stream>>>(weight, whf, wlf);
    gat_prep<<<N_NODES / 32, 128, 0, stream>>>(x, whf, wlf, a, whtf, s1, s2);
    gat_main<<<N_NODES / 16, 512, 0, stream>>>(adj, whtf, s1, s2, out);
}